// Round 8
// baseline (92.611 us; speedup 1.0000x reference)
//
#include <hip/hip_runtime.h>
#include <hip/hip_bf16.h>

typedef __attribute__((ext_vector_type(8))) short short8;
typedef __attribute__((ext_vector_type(4))) float f32x4;
typedef __attribute__((ext_vector_type(4))) unsigned int u32x4;

#define WS_X1_OFF 0u
#define WS_WE_OFF 262144u   // 2048*64*2 bytes of x1 bf16
#define WS_WN_OFF 278528u   // + 16*64*8*2 bytes of w_e2e frags
#define MFMA(a,b,c) __builtin_amdgcn_mfma_f32_16x16x32_bf16(a,b,c,0,0,0)

__device__ __forceinline__ short f2bs(float f) {
  __hip_bfloat16 h = __float2bfloat16(f);   // HW RNE cvt
  return *reinterpret_cast<short*>(&h);
}
__device__ __forceinline__ short8 cvt8v(f32x4 a, f32x4 b) {
  short8 t;
  t[0]=f2bs(a[0]); t[1]=f2bs(a[1]); t[2]=f2bs(a[2]); t[3]=f2bs(a[3]);
  t[4]=f2bs(b[0]); t[5]=f2bs(b[1]); t[6]=f2bs(b[2]); t[7]=f2bs(b[3]);
  return t;
}
__device__ __forceinline__ short8 mask8(short8 v, unsigned int m) {
  u32x4 u; __builtin_memcpy(&u, &v, 16);
  u[0]&=m; u[1]&=m; u[2]&=m; u[3]&=m;
  short8 t; __builtin_memcpy(&t, &u, 16);
  return t;
}

// ---------------- setup kernel: x1 = relu(x@w_n2e+b) as bf16; weight frags ----
__global__ __launch_bounds__(256) void gnn_pre(
    const float* __restrict__ x, const float* __restrict__ w_n2e,
    const float* __restrict__ b_n2e, const float* __restrict__ w_e2e,
    const float* __restrict__ w_e2n, unsigned short* __restrict__ x1ws,
    unsigned short* __restrict__ wEf, unsigned short* __restrict__ wNf)
{
  int blk = blockIdx.x, tid = threadIdx.x;
  if (blk < 512) {                       // x1: 2048 rows x 64 feats
    int idx = blk * 256 + tid;
    int row = idx >> 6, f = idx & 63;
    float s = b_n2e[f];
    const float* xr = x + (size_t)row * 64;
    #pragma unroll 8
    for (int k = 0; k < 64; k++) s += xr[k] * w_n2e[k * 64 + f];
    x1ws[idx] = (unsigned short)f2bs(fmaxf(s, 0.f));
  } else if (blk < 516) {                // w_e2e -> 16 B-frags (ks0..3, n0..3)
    int t = (blk - 512) * 256 + tid;
    int frag = t >> 6, lane = t & 63;
    int ks = frag >> 2, n = frag & 3, g = lane >> 4, r = lane & 15;
    unsigned short* dst = wEf + frag * 512 + lane * 8;
    #pragma unroll
    for (int e = 0; e < 8; e++)
      dst[e] = (unsigned short)f2bs(w_e2e[(ks * 32 + g * 8 + e) * 64 + n * 16 + r]);
  } else {                               // w_e2n -> 8 B-frags (ks0..1, n0..3)
    int t = (blk - 516) * 256 + tid;
    int frag = t >> 6, lane = t & 63;
    int ks = frag >> 2, n = frag & 3, g = lane >> 4, r = lane & 15;
    unsigned short* dst = wNf + frag * 512 + lane * 8;
    #pragma unroll
    for (int e = 0; e < 8; e++)
      dst[e] = (unsigned short)f2bs(w_e2n[(ks * 32 + g * 8 + e) * 64 + n * 16 + r]);
  }
}

// ---------------- main fused kernel -------------------------------------------
// 256 blocks x 512 threads (8 waves). Block owns 8 consecutive (b,i) tiles.
// W stages into LDS via global_load_lds (async DMA, no VGPR cost), double-
// buffered. EVERYTHING in the tile loop is wave-private (each wave DMAs and
// reads only its own 32 rows) -> no __syncthreads in the loop, no convoy.
// vmcnt discipline: DMA(t+1) is issued mid-iter t; the wait at iter-start is
// s_waitcnt vmcnt(8), which tolerates exactly the 8 newest VMEM ops (the
// prefetch) and is always safe because >=40 ops (W_new stores etc.) separate
// DMA(t) from its wait. Reg-staged prefetch is dead: R2/R4/R7 all spilled.
// LDS swizzle: chunk_phys = chunk_log ^ (row&15), applied on BOTH the DMA
// global source and the f32x4 reads (both-sides rule) -> <=4-way conflicts.
__global__ __launch_bounds__(512, 2) void gnn_main(
    const float* __restrict__ A, const float* __restrict__ W,
    const float* __restrict__ x,
    const float* __restrict__ b_e2e, const float* __restrict__ b_e2n,
    const float* __restrict__ w_n2n, const float* __restrict__ b_n2n,
    const unsigned short* __restrict__ x1ws,
    const unsigned short* __restrict__ wEf,
    const unsigned short* __restrict__ wNf,
    float* __restrict__ out)
{
  __shared__ __align__(16) char Wbuf[2][8][8192];  // [stage][wave][32 rows x 256B]
  __shared__ __align__(16) float Aall[8][256];     // per-tile A rows
  __shared__ float Ainv[8];
  __shared__ float x2s[8][8][64];                  // [tile][wave][feat]

  const int tid = threadIdx.x;
  const int w = tid >> 6, l = tid & 63, g = l >> 4, r = l & 15;
  const size_t bi0 = (size_t)blockIdx.x * 8;       // 8 tiles, same b (256%8==0)
  const int b = (int)(bi0 >> 8);
  const int j0 = w * 32;
  const int lrow = l >> 4;                          // 0..3
  const int lch  = l & 15;

  // ---- prologue: wave w loads tile w's A row + its 1-norm ----
  {
    float4 av = *(const float4*)(A + (bi0 + w) * 256 + l * 4);
    *(float4*)(&Aall[w][l * 4]) = av;
    float sum = fabsf(av.x) + fabsf(av.y) + fabsf(av.z) + fabsf(av.w);
    #pragma unroll
    for (int o = 32; o; o >>= 1) sum += __shfl_xor(sum, o, 64);
    if (l == 0) Ainv[w] = 1.0f / fmaxf(sum, 1e-12f);
  }
  __syncthreads();

  // async DMA of one tile's wave-private 32x64 f32 rows, chunk-swizzled source
  auto dma_tile = [&](int t, int s) {
    const float* Wp = W + (bi0 + t) * 16384;
    #pragma unroll
    for (int k = 0; k < 8; k++) {
      int row = k * 4 + lrow;                      // local row 0..31
      int csw = lch ^ (row & 15);                  // pre-swizzled global chunk
      const float* src = Wp + (size_t)(j0 + row) * 64 + csw * 4;
      __builtin_amdgcn_global_load_lds(
          (const __attribute__((address_space(1))) void*)src,
          (__attribute__((address_space(3))) void*)(&Wbuf[s][w][k * 1024]),
          16, 0, 0);
    }
  };

  dma_tile(0, 0);

  // ---- block-invariant register loads (overlap DMA(0) flight) ----
  short8 x1st[2][2];
  #pragma unroll
  for (int m = 0; m < 2; m++) {
    int jm = j0 + m * 16 + r;
    const unsigned short* q = x1ws + ((size_t)(b * 256 + jm)) * 64 + g * 8;
    x1st[m][0] = *(const short8*)(q);
    x1st[m][1] = *(const short8*)(q + 32);
  }
  short8 bn2[2][4];
  #pragma unroll
  for (int ks = 0; ks < 2; ks++)
    #pragma unroll
    for (int n = 0; n < 4; n++)
      bn2[ks][n] = *(const short8*)(wNf + (ks * 4 + n) * 512 + l * 8);
  float bias1[4], bias2[4];
  #pragma unroll
  for (int n = 0; n < 4; n++) {
    bias1[n] = b_e2e[n * 16 + r];
    bias2[n] = b_e2n[n * 16 + r];
  }

  #pragma unroll 2
  for (int t = 0; t < 8; ++t) {
    const int s = t & 1;
    const size_t bi = bi0 + t;

    // --- wait: DMA(t) complete (tolerate only the 8 newest VMEM ops) ---
    asm volatile("s_waitcnt vmcnt(8)" ::: "memory");
    __builtin_amdgcn_sched_barrier(0);

    const char* wb = (const char*)&Wbuf[s][w][0];
    const float inv = Ainv[t];
    unsigned int msk[2];
    #pragma unroll
    for (int m = 0; m < 2; m++)
      msk[m] = (Aall[t][j0 + m * 16 + r] != 0.0f) ? 0xFFFFFFFFu : 0u;

    // --- frag reads from swizzled LDS + cvt to bf16 ---
    short8 afW[2][2];
    #pragma unroll
    for (int m = 0; m < 2; m++) {
      const int lr = m * 16 + r;
      const char* rb = wb + lr * 256;
      const int e = lr & 15;                       // == r
      f32x4 c0 = *(const f32x4*)(rb + ((2 * g)     ^ e) * 16);
      f32x4 c1 = *(const f32x4*)(rb + ((2 * g + 1) ^ e) * 16);
      f32x4 c2 = *(const f32x4*)(rb + ((2 * g + 8) ^ e) * 16);
      f32x4 c3 = *(const f32x4*)(rb + ((2 * g + 9) ^ e) * 16);
      afW[m][0] = cvt8v(c0, c1);
      afW[m][1] = cvt8v(c2, c3);
    }

    // --- issue DMA(t+1) into the other buffer (flies under compute) ---
    if (t < 7) dma_tile(t + 1, s ^ 1);

    // --- GEMM1: [32x128]@[128x64] per wave (be frags transient from L2) ---
    f32x4 acc[2][4];
    #pragma unroll
    for (int m = 0; m < 2; m++)
      #pragma unroll
      for (int n = 0; n < 4; n++)
        acc[m][n] = (f32x4){0.f, 0.f, 0.f, 0.f};
    #pragma unroll
    for (int ks = 0; ks < 4; ks++) {
      short8 af[2];
      af[0] = (ks < 2) ? afW[0][ks] : mask8(x1st[0][ks - 2], msk[0]);
      af[1] = (ks < 2) ? afW[1][ks] : mask8(x1st[1][ks - 2], msk[1]);
      const unsigned short* bb = wEf + ks * 2048 + l * 8;
      short8 b0 = *(const short8*)(bb);
      short8 b1 = *(const short8*)(bb + 512);
      short8 b2 = *(const short8*)(bb + 1024);
      short8 b3 = *(const short8*)(bb + 1536);
      #pragma unroll
      for (int m = 0; m < 2; m++) {
        acc[m][0] = MFMA(af[m], b0, acc[m][0]);
        acc[m][1] = MFMA(af[m], b1, acc[m][1]);
        acc[m][2] = MFMA(af[m], b2, acc[m][2]);
        acc[m][3] = MFMA(af[m], b3, acc[m][3]);
      }
    }

    // --- epilogue1: bias+relu, NT-store W_new f32; wn bf16 overlays cur buf
    //     (frags already in regs -> wave-private region reuse is safe) ---
    char* wnw = (char*)&Wbuf[s][w][0];
    float* Wout = out + bi * 16384;
    #pragma unroll
    for (int m = 0; m < 2; m++)
      #pragma unroll
      for (int n = 0; n < 4; n++)
        #pragma unroll
        for (int reg = 0; reg < 4; reg++) {
          float v = fmaxf(acc[m][n][reg] + bias1[n], 0.f);
          int row = m * 16 + g * 4 + reg;          // 0..31 within wave tile
          int col = n * 16 + r;
          __builtin_nontemporal_store(v, Wout + (size_t)(j0 + row) * 64 + col);
          int off = row * 128 + col * 2;
          *(unsigned short*)(wnw + (off ^ ((row & 7) << 4))) = (unsigned short)f2bs(v);
        }

    // --- GEMM2: e = relu(W_new @ w_e2n + b): [32x64]@[64x64] per wave ---
    f32x4 acc2[2][4];
    #pragma unroll
    for (int m = 0; m < 2; m++)
      #pragma unroll
      for (int n = 0; n < 4; n++)
        acc2[m][n] = (f32x4){0.f, 0.f, 0.f, 0.f};
    #pragma unroll
    for (int ks = 0; ks < 2; ks++) {
      short8 a2[2];
      #pragma unroll
      for (int m = 0; m < 2; m++) {
        int row = m * 16 + r;
        int off = row * 128 + ks * 64 + g * 16;
        a2[m] = *(const short8*)(wnw + (off ^ ((r & 7) << 4)));
      }
      #pragma unroll
      for (int m = 0; m < 2; m++) {
        acc2[m][0] = MFMA(a2[m], bn2[ks][0], acc2[m][0]);
        acc2[m][1] = MFMA(a2[m], bn2[ks][1], acc2[m][1]);
        acc2[m][2] = MFMA(a2[m], bn2[ks][2], acc2[m][2]);
        acc2[m][3] = MFMA(a2[m], bn2[ks][3], acc2[m][3]);
      }
    }

    // --- epilogue2: bias+relu, x2 partial = sum_j An[j]*e[j][f] (32 rows) ---
    float x2p[4] = {0.f, 0.f, 0.f, 0.f};
    #pragma unroll
    for (int m = 0; m < 2; m++) {
      float An_[4];
      #pragma unroll
      for (int reg = 0; reg < 4; reg++)
        An_[reg] = Aall[t][j0 + m * 16 + g * 4 + reg] * inv;
      #pragma unroll
      for (int n = 0; n < 4; n++)
        #pragma unroll
        for (int reg = 0; reg < 4; reg++) {
          float e2 = fmaxf(acc2[m][n][reg] + bias2[n], 0.f);
          x2p[n] += An_[reg] * e2;
        }
    }
    #pragma unroll
    for (int n = 0; n < 4; n++) {
      x2p[n] += __shfl_xor(x2p[n], 16, 64);
      x2p[n] += __shfl_xor(x2p[n], 32, 64);
    }
    if (l < 16) {
      #pragma unroll
      for (int n = 0; n < 4; n++) x2s[t][w][n * 16 + l] = x2p[n];
    }
  }

  __syncthreads();

  // --- fused node update, all 8 tiles: x_new = relu(concat(x,x2)@w_n2n+b) ---
  {
    int t = tid >> 6, f = tid & 63;                // 512 threads = 8 tiles x 64
    size_t bit = bi0 + t;
    float s2 = b_n2n[f];
    const float* xr = x + bit * 64;
    #pragma unroll 8
    for (int k = 0; k < 64; k++) s2 += xr[k] * w_n2n[k * 64 + f];
    #pragma unroll 8
    for (int k = 0; k < 64; k++) {
      float x2k = (x2s[t][0][k] + x2s[t][1][k]) + (x2s[t][2][k] + x2s[t][3][k])
                + (x2s[t][4][k] + x2s[t][5][k]) + (x2s[t][6][k] + x2s[t][7][k]);
      s2 += x2k * w_n2n[(64 + k) * 64 + f];
    }
    __builtin_nontemporal_store(fmaxf(s2, 0.f),
                                out + (size_t)8 * 256 * 256 * 64 + bit * 64 + f);
  }
}

extern "C" void kernel_launch(void* const* d_in, const int* in_sizes, int n_in,
                              void* d_out, int out_size, void* d_ws, size_t ws_size,
                              hipStream_t stream) {
  const float* A     = (const float*)d_in[0];
  const float* W     = (const float*)d_in[1];
  const float* x     = (const float*)d_in[2];
  const float* w_n2e = (const float*)d_in[3];
  const float* b_n2e = (const float*)d_in[4];
  const float* w_e2e = (const float*)d_in[5];
  const float* b_e2e = (const float*)d_in[6];
  const float* w_e2n = (const float*)d_in[7];
  const float* b_e2n = (const float*)d_in[8];
  const float* w_n2n = (const float*)d_in[9];
  const float* b_n2n = (const float*)d_in[10];

  unsigned short* x1ws = (unsigned short*)((char*)d_ws + WS_X1_OFF);
  unsigned short* wEf  = (unsigned short*)((char*)d_ws + WS_WE_OFF);
  unsigned short* wNf  = (unsigned short*)((char*)d_ws + WS_WN_OFF);

  gnn_pre<<<518, 256, 0, stream>>>(x, w_n2e, b_n2e, w_e2e, w_e2n, x1ws, wEf, wNf);
  gnn_main<<<256, 512, 0, stream>>>(A, W, x, b_e2e, b_e2n, w_n2n, b_n2n,
                                    x1ws, wEf, wNf, (float*)d_out);
}

// Round 9
// 70.774 us; speedup vs baseline: 1.3086x; 1.3086x over previous
//
#include <hip/hip_runtime.h>
#include <hip/hip_bf16.h>

typedef __attribute__((ext_vector_type(8))) short short8;
typedef __attribute__((ext_vector_type(4))) float f32x4;
typedef __attribute__((ext_vector_type(4))) unsigned int u32x4;

#define WS_X1_OFF 0u
#define WS_WE_OFF 262144u   // 2048*64*2 bytes of x1 bf16
#define WS_WN_OFF 278528u   // + 16*64*8*2 bytes of w_e2e frags
#define WS_X2_OFF 286720u   // + 8*64*8*2 bytes of w_e2n frags; x2 partials 4MB
#define WS_NEEDED (286720u + 2048u * 512u * 4u)
#define MFMA(a,b,c) __builtin_amdgcn_mfma_f32_16x16x32_bf16(a,b,c,0,0,0)

__device__ __forceinline__ short f2bs(float f) {
  __hip_bfloat16 h = __float2bfloat16(f);   // HW RNE cvt
  return *reinterpret_cast<short*>(&h);
}
__device__ __forceinline__ short8 cvt8(float4 a, float4 b) {
  short8 t;
  t[0]=f2bs(a.x); t[1]=f2bs(a.y); t[2]=f2bs(a.z); t[3]=f2bs(a.w);
  t[4]=f2bs(b.x); t[5]=f2bs(b.y); t[6]=f2bs(b.z); t[7]=f2bs(b.w);
  return t;
}
__device__ __forceinline__ short8 mask8(short8 v, unsigned int m) {
  u32x4 u; __builtin_memcpy(&u, &v, 16);
  u[0]&=m; u[1]&=m; u[2]&=m; u[3]&=m;
  short8 t; __builtin_memcpy(&t, &u, 16);
  return t;
}

// ---------------- setup kernel: x1 = relu(x@w_n2e+b) as bf16; weight frags ----
__global__ __launch_bounds__(256) void gnn_pre(
    const float* __restrict__ x, const float* __restrict__ w_n2e,
    const float* __restrict__ b_n2e, const float* __restrict__ w_e2e,
    const float* __restrict__ w_e2n, unsigned short* __restrict__ x1ws,
    unsigned short* __restrict__ wEf, unsigned short* __restrict__ wNf)
{
  int blk = blockIdx.x, tid = threadIdx.x;
  if (blk < 512) {                       // x1: 2048 rows x 64 feats
    int idx = blk * 256 + tid;
    int row = idx >> 6, f = idx & 63;
    float s = b_n2e[f];
    const float* xr = x + (size_t)row * 64;
    #pragma unroll 8
    for (int k = 0; k < 64; k++) s += xr[k] * w_n2e[k * 64 + f];
    x1ws[idx] = (unsigned short)f2bs(fmaxf(s, 0.f));
  } else if (blk < 516) {                // w_e2e -> 16 B-frags (ks0..3, n0..3)
    int t = (blk - 512) * 256 + tid;
    int frag = t >> 6, lane = t & 63;
    int ks = frag >> 2, n = frag & 3, g = lane >> 4, r = lane & 15;
    unsigned short* dst = wEf + frag * 512 + lane * 8;
    #pragma unroll
    for (int e = 0; e < 8; e++)
      dst[e] = (unsigned short)f2bs(w_e2e[(ks * 32 + g * 8 + e) * 64 + n * 16 + r]);
  } else {                               // w_e2n -> 8 B-frags (ks0..1, n0..3)
    int t = (blk - 516) * 256 + tid;
    int frag = t >> 6, lane = t & 63;
    int ks = frag >> 2, n = frag & 3, g = lane >> 4, r = lane & 15;
    unsigned short* dst = wNf + frag * 512 + lane * 8;
    #pragma unroll
    for (int e = 0; e < 8; e++)
      dst[e] = (unsigned short)f2bs(w_e2n[(ks * 32 + g * 8 + e) * 64 + n * 16 + r]);
  }
}

// ---------------- decoupled main: 4096 blocks x 256 thr, ZERO block barriers --
// Each wave owns 32 rows of one (b,i) tile (32-row body proven spill-free under
// cap 128: R5 counters clean). No Arow LDS (A re-read as L1-hot scalars), no
// __syncthreads, no tail: wave stores its x2 partial (64 f32) to ws and
// retires. Node update runs in gnn_node. Pipelining is DEAD: R4/R7 (reg) and
// R8 (LDS-DMA) all inflated traffic; single-tile stream-through is the winner.
__global__ __launch_bounds__(256, 4) void gnn_main_nb(
    const float* __restrict__ A, const float* __restrict__ W,
    const float* __restrict__ b_e2e, const float* __restrict__ b_e2n,
    const unsigned short* __restrict__ x1ws,
    const unsigned short* __restrict__ wEf,
    const unsigned short* __restrict__ wNf,
    float* __restrict__ out, float* __restrict__ x2ws)
{
  __shared__ __align__(16) char wn[4][4096];    // per-wave 32x64 bf16 W_new tile

  const int tid = threadIdx.x;
  const int w = tid >> 6, l = tid & 63, g = l >> 4, r = l & 15;
  const size_t bi = blockIdx.x >> 1;
  const int half = blockIdx.x & 1;
  const int b = (int)(bi >> 8);
  const int j0 = half * 128 + w * 32;
  const int slot = half * 4 + w;                // 0..7 partial slot per bi
  char* wnw = &wn[w][0];

  // --- W rows first (the HBM stream) ---
  const float* Wp = W + bi * 16384;
  float4 wst[2][4];
  #pragma unroll
  for (int m = 0; m < 2; m++) {
    int jm = j0 + m * 16 + r;
    const float* p = Wp + (size_t)jm * 64 + g * 8;
    wst[m][0] = *(const float4*)(p);
    wst[m][1] = *(const float4*)(p + 4);
    wst[m][2] = *(const float4*)(p + 32);
    wst[m][3] = *(const float4*)(p + 36);
  }

  // --- A row: 1-norm (full row via float4) + masks (scalar, L1-hot) ---
  const float* Ap = A + bi * 256;
  float4 av = *(const float4*)(Ap + l * 4);
  float sum = fabsf(av.x) + fabsf(av.y) + fabsf(av.z) + fabsf(av.w);
  #pragma unroll
  for (int o = 32; o; o >>= 1) sum += __shfl_xor(sum, o, 64);
  const float inv = 1.0f / fmaxf(sum, 1e-12f);
  unsigned int msk[2];
  #pragma unroll
  for (int m = 0; m < 2; m++)
    msk[m] = (Ap[j0 + m * 16 + r] != 0.0f) ? 0xFFFFFFFFu : 0u;

  // --- x1 rows (L2-resident) ---
  short8 x1st[2][2];
  #pragma unroll
  for (int m = 0; m < 2; m++) {
    int jm = j0 + m * 16 + r;
    const unsigned short* q = x1ws + ((size_t)(b * 256 + jm)) * 64 + g * 8;
    x1st[m][0] = *(const short8*)(q);
    x1st[m][1] = *(const short8*)(q + 32);
  }

  // --- GEMM1: [32x128]@[128x64], per-ks streamed B-frags (transient regs) ---
  f32x4 acc[2][4];
  #pragma unroll
  for (int m = 0; m < 2; m++)
    #pragma unroll
    for (int n = 0; n < 4; n++)
      acc[m][n] = (f32x4){0.f, 0.f, 0.f, 0.f};
  #pragma unroll
  for (int ks = 0; ks < 4; ks++) {
    short8 af[2];
    af[0] = (ks < 2) ? cvt8(wst[0][ks * 2], wst[0][ks * 2 + 1]) : mask8(x1st[0][ks - 2], msk[0]);
    af[1] = (ks < 2) ? cvt8(wst[1][ks * 2], wst[1][ks * 2 + 1]) : mask8(x1st[1][ks - 2], msk[1]);
    const unsigned short* bb = wEf + ks * 2048 + l * 8;
    short8 b0 = *(const short8*)(bb);
    short8 b1 = *(const short8*)(bb + 512);
    short8 b2 = *(const short8*)(bb + 1024);
    short8 b3 = *(const short8*)(bb + 1536);
    #pragma unroll
    for (int m = 0; m < 2; m++) {
      acc[m][0] = MFMA(af[m], b0, acc[m][0]);
      acc[m][1] = MFMA(af[m], b1, acc[m][1]);
      acc[m][2] = MFMA(af[m], b2, acc[m][2]);
      acc[m][3] = MFMA(af[m], b3, acc[m][3]);
    }
  }

  // --- epilogue1: bias+relu, NT-store W_new f32, stash bf16 in swizzled LDS ---
  float bias1[4];
  #pragma unroll
  for (int n = 0; n < 4; n++) bias1[n] = b_e2e[n * 16 + r];
  float* Wout = out + bi * 16384;
  #pragma unroll
  for (int m = 0; m < 2; m++)
    #pragma unroll
    for (int n = 0; n < 4; n++)
      #pragma unroll
      for (int reg = 0; reg < 4; reg++) {
        float v = fmaxf(acc[m][n][reg] + bias1[n], 0.f);
        int row = m * 16 + g * 4 + reg;          // 0..31 within wave tile
        int col = n * 16 + r;
        __builtin_nontemporal_store(v, Wout + (size_t)(j0 + row) * 64 + col);
        int off = row * 128 + col * 2;
        *(unsigned short*)(wnw + (off ^ ((row & 7) << 4))) = (unsigned short)f2bs(v);
      }

  // --- GEMM2: e = relu(W_new @ w_e2n + b): [32x64]@[64x64] per wave ---
  f32x4 acc2[2][4];
  #pragma unroll
  for (int m = 0; m < 2; m++)
    #pragma unroll
    for (int n = 0; n < 4; n++)
      acc2[m][n] = (f32x4){0.f, 0.f, 0.f, 0.f};
  #pragma unroll
  for (int ks = 0; ks < 2; ks++) {
    short8 a2[2];
    #pragma unroll
    for (int m = 0; m < 2; m++) {
      int row = m * 16 + r;
      int off = row * 128 + ks * 64 + g * 16;
      a2[m] = *(const short8*)(wnw + (off ^ ((r & 7) << 4)));
    }
    const unsigned short* bb = wNf + ks * 2048 + l * 8;
    short8 b0 = *(const short8*)(bb);
    short8 b1 = *(const short8*)(bb + 512);
    short8 b2 = *(const short8*)(bb + 1024);
    short8 b3 = *(const short8*)(bb + 1536);
    #pragma unroll
    for (int m = 0; m < 2; m++) {
      acc2[m][0] = MFMA(a2[m], b0, acc2[m][0]);
      acc2[m][1] = MFMA(a2[m], b1, acc2[m][1]);
      acc2[m][2] = MFMA(a2[m], b2, acc2[m][2]);
      acc2[m][3] = MFMA(a2[m], b3, acc2[m][3]);
    }
  }

  // --- epilogue2: bias+relu, An-weighted reduce over this wave's 32 rows ---
  float bias2[4];
  #pragma unroll
  for (int n = 0; n < 4; n++) bias2[n] = b_e2n[n * 16 + r];
  float x2p[4] = {0.f, 0.f, 0.f, 0.f};
  #pragma unroll
  for (int m = 0; m < 2; m++) {
    float An_[4];
    #pragma unroll
    for (int reg = 0; reg < 4; reg++)
      An_[reg] = Ap[j0 + m * 16 + g * 4 + reg] * inv;   // L1-hot scalar
    #pragma unroll
    for (int n = 0; n < 4; n++)
      #pragma unroll
      for (int reg = 0; reg < 4; reg++) {
        float e2 = fmaxf(acc2[m][n][reg] + bias2[n], 0.f);
        x2p[n] += An_[reg] * e2;
      }
  }
  #pragma unroll
  for (int n = 0; n < 4; n++) {
    x2p[n] += __shfl_xor(x2p[n], 16, 64);
    x2p[n] += __shfl_xor(x2p[n], 32, 64);
  }
  if (l < 16) {
    float* dst = x2ws + bi * 512 + slot * 64;
    #pragma unroll
    for (int n = 0; n < 4; n++) dst[n * 16 + l] = x2p[n];
  }
  // wave retires — no barrier, no tail.
}

// ---------------- node kernel: x_new = relu(concat(x, sum8(x2p)) @ w_n2n + b) -
__global__ __launch_bounds__(256) void gnn_node(
    const float* __restrict__ x, const float* __restrict__ w_n2n,
    const float* __restrict__ b_n2n, const float* __restrict__ x2ws,
    float* __restrict__ out)
{
  __shared__ float wl[128 * 64];      // 32KB, L2->LDS once per block
  __shared__ float xs[16][64];
  __shared__ float x2r[16][64];
  const int tid = threadIdx.x;
  const size_t bi0 = (size_t)blockIdx.x * 16;   // 128 blocks x 16 nodes

  #pragma unroll
  for (int i = 0; i < 8; i++)
    *(float4*)(&wl[(tid + i * 256) * 4]) = *(const float4*)(w_n2n + (tid + i * 256) * 4);
  *(float4*)(&xs[0][0] + tid * 4) = *(const float4*)(x + bi0 * 64 + tid * 4);
  {
    int rr = tid >> 4, fq = (tid & 15) * 4;
    const float* p = x2ws + (bi0 + rr) * 512 + fq;
    float4 sacc = {0.f, 0.f, 0.f, 0.f};
    #pragma unroll
    for (int q = 0; q < 8; q++) {
      float4 v = *(const float4*)(p + q * 64);
      sacc.x += v.x; sacc.y += v.y; sacc.z += v.z; sacc.w += v.w;
    }
    *(float4*)(&x2r[rr][fq]) = sacc;
  }
  __syncthreads();

  const int f = tid & 63, r0 = tid >> 6;
  #pragma unroll
  for (int it = 0; it < 4; it++) {
    int row = r0 * 4 + it;
    float s2 = b_n2n[f];
    #pragma unroll 8
    for (int k = 0; k < 64; k++) s2 += xs[row][k] * wl[k * 64 + f];
    #pragma unroll 8
    for (int k = 0; k < 64; k++) s2 += x2r[row][k] * wl[(64 + k) * 64 + f];
    __builtin_nontemporal_store(fmaxf(s2, 0.f),
        out + (size_t)8 * 256 * 256 * 64 + (bi0 + row) * 64 + f);
  }
}

// ---------------- fallback fused main (exact R6 best, used if ws too small) ---
__global__ __launch_bounds__(256, 2) void gnn_main_fused(
    const float* __restrict__ A, const float* __restrict__ W,
    const float* __restrict__ x,
    const float* __restrict__ b_e2e, const float* __restrict__ b_e2n,
    const float* __restrict__ w_n2n, const float* __restrict__ b_n2n,
    const unsigned short* __restrict__ x1ws,
    const unsigned short* __restrict__ wEf,
    const unsigned short* __restrict__ wNf,
    float* __restrict__ out)
{
  __shared__ __align__(16) float Arow[4][256];
  __shared__ float x2s[4][64];
  __shared__ __align__(16) char wn[4 * 8192];

  const int tid = threadIdx.x;
  const int w = tid >> 6, l = tid & 63, g = l >> 4, r = l & 15;
  const size_t bi = blockIdx.x;
  const int b = blockIdx.x >> 8;
  const int j0 = w * 64;

  const float* Wp = W + bi * 256 * 64;
  float4 wst[4][4];
  #pragma unroll
  for (int m = 0; m < 4; m++) {
    int jm = j0 + m * 16 + r;
    const float* p = Wp + (size_t)jm * 64 + g * 8;
    wst[m][0] = *(const float4*)(p);
    wst[m][1] = *(const float4*)(p + 4);
    wst[m][2] = *(const float4*)(p + 32);
    wst[m][3] = *(const float4*)(p + 36);
  }
  short8 x1st[4][2];
  #pragma unroll
  for (int m = 0; m < 4; m++) {
    int jm = j0 + m * 16 + r;
    const unsigned short* q = x1ws + ((size_t)(b * 256 + jm)) * 64 + g * 8;
    x1st[m][0] = *(const short8*)(q);
    x1st[m][1] = *(const short8*)(q + 32);
  }
  float4 av = *(const float4*)(A + bi * 256 + l * 4);
  *(float4*)(&Arow[w][l * 4]) = av;
  float s = fabsf(av.x) + fabsf(av.y) + fabsf(av.z) + fabsf(av.w);
  #pragma unroll
  for (int o = 32; o; o >>= 1) s += __shfl_xor(s, o, 64);
  const float inv = 1.0f / fmaxf(s, 1e-12f);
  short8 be[4][4];
  #pragma unroll
  for (int ks = 0; ks < 4; ks++)
    #pragma unroll
    for (int n = 0; n < 4; n++)
      be[ks][n] = *(const short8*)(wEf + (ks * 4 + n) * 512 + l * 8);
  __builtin_amdgcn_wave_barrier();
  short8 af[4][4];
  #pragma unroll
  for (int m = 0; m < 4; m++) {
    int jm = j0 + m * 16 + r;
    #pragma unroll
    for (int h = 0; h < 2; h++)
      af[m][h] = cvt8(wst[m][h * 2], wst[m][h * 2 + 1]);
    unsigned int msk = (Arow[w][jm] != 0.0f) ? 0xFFFFFFFFu : 0u;
    #pragma unroll
    for (int h = 0; h < 2; h++)
      af[m][2 + h] = mask8(x1st[m][h], msk);
  }
  f32x4 acc[4][4];
  #pragma unroll
  for (int m = 0; m < 4; m++)
    #pragma unroll
    for (int n = 0; n < 4; n++)
      acc[m][n] = (f32x4){0.f, 0.f, 0.f, 0.f};
  #pragma unroll
  for (int ks = 0; ks < 4; ks++)
    #pragma unroll
    for (int m = 0; m < 4; m++)
      #pragma unroll
      for (int n = 0; n < 4; n++)
        acc[m][n] = MFMA(af[m][ks], be[ks][n], acc[m][n]);
  float bias1[4];
  #pragma unroll
  for (int n = 0; n < 4; n++) bias1[n] = b_e2e[n * 16 + r];
  float* Wout = out + bi * 256 * 64;
  char* wnw = wn + w * 8192;
  #pragma unroll
  for (int m = 0; m < 4; m++)
    #pragma unroll
    for (int n = 0; n < 4; n++)
      #pragma unroll
      for (int reg = 0; reg < 4; reg++) {
        float v = fmaxf(acc[m][n][reg] + bias1[n], 0.f);
        int row = m * 16 + g * 4 + reg;
        int col = n * 16 + r;
        __builtin_nontemporal_store(v, Wout + (size_t)(j0 + row) * 64 + col);
        int off = row * 128 + col * 2;
        *(unsigned short*)(wnw + (off ^ ((row & 7) << 4))) = (unsigned short)f2bs(v);
      }
  short8 bn2[2][4];
  #pragma unroll
  for (int ks = 0; ks < 2; ks++)
    #pragma unroll
    for (int n = 0; n < 4; n++)
      bn2[ks][n] = *(const short8*)(wNf + (ks * 4 + n) * 512 + l * 8);
  f32x4 acc2[4][4];
  #pragma unroll
  for (int m = 0; m < 4; m++)
    #pragma unroll
    for (int n = 0; n < 4; n++)
      acc2[m][n] = (f32x4){0.f, 0.f, 0.f, 0.f};
  #pragma unroll
  for (int ks = 0; ks < 2; ks++) {
    short8 a2[4];
    #pragma unroll
    for (int m = 0; m < 4; m++) {
      int row = m * 16 + r;
      int off = row * 128 + ks * 64 + g * 16;
      a2[m] = *(const short8*)(wnw + (off ^ ((r & 7) << 4)));
    }
    #pragma unroll
    for (int m = 0; m < 4; m++)
      #pragma unroll
      for (int n = 0; n < 4; n++)
        acc2[m][n] = MFMA(a2[m], bn2[ks][n], acc2[m][n]);
  }
  float bias2[4];
  #pragma unroll
  for (int n = 0; n < 4; n++) bias2[n] = b_e2n[n * 16 + r];
  float x2p[4] = {0.f, 0.f, 0.f, 0.f};
  #pragma unroll
  for (int m = 0; m < 4; m++) {
    float An_[4];
    #pragma unroll
    for (int reg = 0; reg < 4; reg++)
      An_[reg] = Arow[w][j0 + m * 16 + g * 4 + reg] * inv;
    #pragma unroll
    for (int n = 0; n < 4; n++)
      #pragma unroll
      for (int reg = 0; reg < 4; reg++) {
        float e = fmaxf(acc2[m][n][reg] + bias2[n], 0.f);
        x2p[n] += An_[reg] * e;
      }
  }
  #pragma unroll
  for (int n = 0; n < 4; n++) {
    x2p[n] += __shfl_xor(x2p[n], 16, 64);
    x2p[n] += __shfl_xor(x2p[n], 32, 64);
  }
  if (l < 16) {
    #pragma unroll
    for (int n = 0; n < 4; n++) x2s[w][n * 16 + l] = x2p[n];
  }
  __syncthreads();
  if (tid < 64) {
    float s2 = b_n2n[tid];
    const float* xr = x + bi * 64;
    #pragma unroll 8
    for (int k = 0; k < 64; k++) s2 += xr[k] * w_n2n[k * 64 + tid];
    #pragma unroll 8
    for (int k = 0; k < 64; k++) {
      float x2k = x2s[0][k] + x2s[1][k] + x2s[2][k] + x2s[3][k];
      s2 += x2k * w_n2n[(64 + k) * 64 + tid];
    }
    __builtin_nontemporal_store(fmaxf(s2, 0.f),
                                out + (size_t)8 * 256 * 256 * 64 + bi * 64 + tid);
  }
}

extern "C" void kernel_launch(void* const* d_in, const int* in_sizes, int n_in,
                              void* d_out, int out_size, void* d_ws, size_t ws_size,
                              hipStream_t stream) {
  const float* A     = (const float*)d_in[0];
  const float* W     = (const float*)d_in[1];
  const float* x     = (const float*)d_in[2];
  const float* w_n2e = (const float*)d_in[3];
  const float* b_n2e = (const float*)d_in[4];
  const float* w_e2e = (const float*)d_in[5];
  const float* b_e2e = (const float*)d_in[6];
  const float* w_e2n = (const float*)d_in[7];
  const float* b_e2n = (const float*)d_in[8];
  const float* w_n2n = (const float*)d_in[9];
  const float* b_n2n = (const float*)d_in[10];

  unsigned short* x1ws = (unsigned short*)((char*)d_ws + WS_X1_OFF);
  unsigned short* wEf  = (unsigned short*)((char*)d_ws + WS_WE_OFF);
  unsigned short* wNf  = (unsigned short*)((char*)d_ws + WS_WN_OFF);
  float*          x2ws = (float*)((char*)d_ws + WS_X2_OFF);

  gnn_pre<<<518, 256, 0, stream>>>(x, w_n2e, b_n2e, w_e2e, w_e2n, x1ws, wEf, wNf);
  if (ws_size >= (size_t)WS_NEEDED) {
    gnn_main_nb<<<4096, 256, 0, stream>>>(A, W, b_e2e, b_e2n,
                                          x1ws, wEf, wNf, (float*)d_out, x2ws);
    gnn_node<<<128, 256, 0, stream>>>(x, w_n2n, b_n2n, x2ws, (float*)d_out);
  } else {
    gnn_main_fused<<<2048, 256, 0, stream>>>(A, W, x, b_e2e, b_e2n, w_n2n, b_n2n,
                                             x1ws, wEf, wNf, (float*)d_out);
  }
}

// Round 10
// 65.939 us; speedup vs baseline: 1.4045x; 1.0733x over previous
//
#include <hip/hip_runtime.h>
#include <hip/hip_bf16.h>

typedef __attribute__((ext_vector_type(8))) short short8;
typedef __attribute__((ext_vector_type(4))) float f32x4;
typedef __attribute__((ext_vector_type(4))) unsigned int u32x4;

#define WS_X1_OFF 0u
#define WS_WE_OFF 262144u   // 2048*64*2 bytes of x1 bf16
#define WS_WN_OFF 278528u   // + 16*64*8*2 bytes of w_e2e frags
#define WS_X2_OFF 286720u   // + 8*64*8*2 bytes of w_e2n frags; x2 partials 4MB
#define WS_NEEDED (286720u + 2048u * 512u * 4u)
#define MFMA(a,b,c) __builtin_amdgcn_mfma_f32_16x16x32_bf16(a,b,c,0,0,0)

__device__ __forceinline__ short f2bs(float f) {
  __hip_bfloat16 h = __float2bfloat16(f);   // HW RNE cvt
  return *reinterpret_cast<short*>(&h);
}
__device__ __forceinline__ short8 cvt8(float4 a, float4 b) {
  short8 t;
  t[0]=f2bs(a.x); t[1]=f2bs(a.y); t[2]=f2bs(a.z); t[3]=f2bs(a.w);
  t[4]=f2bs(b.x); t[5]=f2bs(b.y); t[6]=f2bs(b.z); t[7]=f2bs(b.w);
  return t;
}
__device__ __forceinline__ short8 mask8(short8 v, unsigned int m) {
  u32x4 u; __builtin_memcpy(&u, &v, 16);
  u[0]&=m; u[1]&=m; u[2]&=m; u[3]&=m;
  short8 t; __builtin_memcpy(&t, &u, 16);
  return t;
}
// streaming store: sc0 sc1 nt = system-scope + non-temporal -> attempt true
// no-allocate so the 134MB W_new stream stops evicting W from L2/L3.
// No "memory" clobber on purpose: nothing in-kernel reads out[], and a clobber
// would pin LDS/VMEM scheduling around each of the 32 stores.
__device__ __forceinline__ void st_stream(float* p, float v) {
  asm volatile("global_store_dword %0, %1, off sc0 sc1 nt" :: "v"(p), "v"(v));
}

// ---------------- setup kernel: x1 = relu(x@w_n2e+b) as bf16; weight frags ----
__global__ __launch_bounds__(256) void gnn_pre(
    const float* __restrict__ x, const float* __restrict__ w_n2e,
    const float* __restrict__ b_n2e, const float* __restrict__ w_e2e,
    const float* __restrict__ w_e2n, unsigned short* __restrict__ x1ws,
    unsigned short* __restrict__ wEf, unsigned short* __restrict__ wNf)
{
  int blk = blockIdx.x, tid = threadIdx.x;
  if (blk < 512) {                       // x1: 2048 rows x 64 feats
    int idx = blk * 256 + tid;
    int row = idx >> 6, f = idx & 63;
    float s = b_n2e[f];
    const float* xr = x + (size_t)row * 64;
    #pragma unroll 8
    for (int k = 0; k < 64; k++) s += xr[k] * w_n2e[k * 64 + f];
    x1ws[idx] = (unsigned short)f2bs(fmaxf(s, 0.f));
  } else if (blk < 516) {                // w_e2e -> 16 B-frags (ks0..3, n0..3)
    int t = (blk - 512) * 256 + tid;
    int frag = t >> 6, lane = t & 63;
    int ks = frag >> 2, n = frag & 3, g = lane >> 4, r = lane & 15;
    unsigned short* dst = wEf + frag * 512 + lane * 8;
    #pragma unroll
    for (int e = 0; e < 8; e++)
      dst[e] = (unsigned short)f2bs(w_e2e[(ks * 32 + g * 8 + e) * 64 + n * 16 + r]);
  } else {                               // w_e2n -> 8 B-frags (ks0..1, n0..3)
    int t = (blk - 516) * 256 + tid;
    int frag = t >> 6, lane = t & 63;
    int ks = frag >> 2, n = frag & 3, g = lane >> 4, r = lane & 15;
    unsigned short* dst = wNf + frag * 512 + lane * 8;
    #pragma unroll
    for (int e = 0; e < 8; e++)
      dst[e] = (unsigned short)f2bs(w_e2n[(ks * 32 + g * 8 + e) * 64 + n * 16 + r]);
  }
}

// ---------------- decoupled main: 4096 blocks x 256 thr, ZERO block barriers --
// R9 base + two levers:
// (1) vmcnt-FIFO ordering: VMEM returns are IN ISSUE ORDER. All L2/L1-hot
//     operands (A scalars, x1, biases, be23, bn2) are issued BEFORE the 16
//     HBM W loads; the x1-dependent ks=2,3 MFMAs execute DURING W flight;
//     bn2/An8 no longer queue behind the 32 stores.
// (2) st_stream (sc0 sc1 nt) on W_new: attempt no-allocate to keep W L3-hot.
// launch_bounds(256,2): ~220 unified regs, cap 256 -> no spill (R2/R4/R7
// lesson: spills show as FETCH/WRITE inflation; verify in counters).
__global__ __launch_bounds__(256, 2) void gnn_main_nb(
    const float* __restrict__ A, const float* __restrict__ W,
    const float* __restrict__ b_e2e, const float* __restrict__ b_e2n,
    const unsigned short* __restrict__ x1ws,
    const unsigned short* __restrict__ wEf,
    const unsigned short* __restrict__ wNf,
    float* __restrict__ out, float* __restrict__ x2ws)
{
  __shared__ __align__(16) char wn[4][4096];    // per-wave 32x64 bf16 W_new tile

  const int tid = threadIdx.x;
  const int w = tid >> 6, l = tid & 63, g = l >> 4, r = l & 15;
  const size_t bi = blockIdx.x >> 1;
  const int half = blockIdx.x & 1;
  const int b = (int)(bi >> 8);
  const int j0 = half * 128 + w * 32;
  const int slot = half * 4 + w;                // 0..7 partial slot per bi
  char* wnw = &wn[w][0];

  // ---- L2/L1-hot loads FIRST ----
  const float* Ap = A + bi * 256;
  float4 av = *(const float4*)(Ap + l * 4);
  float am[2]; am[0] = Ap[j0 + r]; am[1] = Ap[j0 + 16 + r];
  float An8[2][4];
  #pragma unroll
  for (int m = 0; m < 2; m++)
    #pragma unroll
    for (int reg = 0; reg < 4; reg++)
      An8[m][reg] = Ap[j0 + m * 16 + g * 4 + reg];
  short8 x1st[2][2];
  #pragma unroll
  for (int m = 0; m < 2; m++) {
    const unsigned short* q = x1ws + ((size_t)(b * 256 + j0 + m * 16 + r)) * 64 + g * 8;
    x1st[m][0] = *(const short8*)(q);
    x1st[m][1] = *(const short8*)(q + 32);
  }
  float bias1[4], bias2[4];
  #pragma unroll
  for (int n = 0; n < 4; n++) {
    bias1[n] = b_e2e[n * 16 + r];
    bias2[n] = b_e2n[n * 16 + r];
  }
  short8 be2[4], be3[4];                        // w_e2e frags for ks=2,3
  #pragma unroll
  for (int n = 0; n < 4; n++) {
    be2[n] = *(const short8*)(wEf + 2 * 2048 + n * 512 + l * 8);
    be3[n] = *(const short8*)(wEf + 3 * 2048 + n * 512 + l * 8);
  }
  short8 bn2[2][4];                             // w_e2n frags (used in GEMM2)
  #pragma unroll
  for (int ks = 0; ks < 2; ks++)
    #pragma unroll
    for (int n = 0; n < 4; n++)
      bn2[ks][n] = *(const short8*)(wNf + (ks * 4 + n) * 512 + l * 8);

  // ---- W rows: ks-half-major issue (ks0's 8 chunks enter the FIFO first) ----
  const float* Wp = W + bi * 16384;
  float4 wst[2][4];
  #pragma unroll
  for (int h = 0; h < 2; h++)
    #pragma unroll
    for (int m = 0; m < 2; m++) {
      const float* p = Wp + (size_t)(j0 + m * 16 + r) * 64 + g * 8 + h * 32;
      wst[m][2 * h]     = *(const float4*)(p);
      wst[m][2 * h + 1] = *(const float4*)(p + 4);
    }

  // ---- VALU while W flies: 1-norm + masks ----
  float sum = fabsf(av.x) + fabsf(av.y) + fabsf(av.z) + fabsf(av.w);
  #pragma unroll
  for (int o = 32; o; o >>= 1) sum += __shfl_xor(sum, o, 64);
  const float inv = 1.0f / fmaxf(sum, 1e-12f);
  unsigned int msk[2];
  msk[0] = (am[0] != 0.0f) ? 0xFFFFFFFFu : 0u;
  msk[1] = (am[1] != 0.0f) ? 0xFFFFFFFFu : 0u;

  f32x4 acc[2][4];
  #pragma unroll
  for (int m = 0; m < 2; m++)
    #pragma unroll
    for (int n = 0; n < 4; n++)
      acc[m][n] = (f32x4){0.f, 0.f, 0.f, 0.f};

  // ---- GEMM1 ks=2,3 FIRST: all operands L2-hot -> MFMAs run under W flight
  {
    short8 a0 = mask8(x1st[0][0], msk[0]);
    short8 a1 = mask8(x1st[1][0], msk[1]);
    #pragma unroll
    for (int n = 0; n < 4; n++) {
      acc[0][n] = MFMA(a0, be2[n], acc[0][n]);
      acc[1][n] = MFMA(a1, be2[n], acc[1][n]);
    }
    a0 = mask8(x1st[0][1], msk[0]);
    a1 = mask8(x1st[1][1], msk[1]);
    #pragma unroll
    for (int n = 0; n < 4; n++) {
      acc[0][n] = MFMA(a0, be3[n], acc[0][n]);
      acc[1][n] = MFMA(a1, be3[n], acc[1][n]);
    }
  }

  // ---- GEMM1 ks=0,1: W-dependent (wEf ks01 frags streamed) ----
  #pragma unroll
  for (int ks = 0; ks < 2; ks++) {
    short8 af0 = cvt8(wst[0][2 * ks], wst[0][2 * ks + 1]);
    short8 af1 = cvt8(wst[1][2 * ks], wst[1][2 * ks + 1]);
    const unsigned short* bb = wEf + ks * 2048 + l * 8;
    short8 b0 = *(const short8*)(bb);
    short8 b1 = *(const short8*)(bb + 512);
    short8 b2 = *(const short8*)(bb + 1024);
    short8 b3 = *(const short8*)(bb + 1536);
    acc[0][0] = MFMA(af0, b0, acc[0][0]);
    acc[0][1] = MFMA(af0, b1, acc[0][1]);
    acc[0][2] = MFMA(af0, b2, acc[0][2]);
    acc[0][3] = MFMA(af0, b3, acc[0][3]);
    acc[1][0] = MFMA(af1, b0, acc[1][0]);
    acc[1][1] = MFMA(af1, b1, acc[1][1]);
    acc[1][2] = MFMA(af1, b2, acc[1][2]);
    acc[1][3] = MFMA(af1, b3, acc[1][3]);
  }

  // ---- epilogue1: bias+relu, STREAM-store W_new f32, bf16 to swizzled LDS ---
  float* Wout = out + bi * 16384;
  #pragma unroll
  for (int m = 0; m < 2; m++)
    #pragma unroll
    for (int n = 0; n < 4; n++)
      #pragma unroll
      for (int reg = 0; reg < 4; reg++) {
        float v = fmaxf(acc[m][n][reg] + bias1[n], 0.f);
        int row = m * 16 + g * 4 + reg;          // 0..31 within wave tile
        int col = n * 16 + r;
        st_stream(Wout + (size_t)(j0 + row) * 64 + col, v);
        int off = row * 128 + col * 2;
        *(unsigned short*)(wnw + (off ^ ((row & 7) << 4))) = (unsigned short)f2bs(v);
      }

  // ---- GEMM2: e = relu(W_new @ w_e2n + b): [32x64]@[64x64] per wave ----
  f32x4 acc2[2][4];
  #pragma unroll
  for (int m = 0; m < 2; m++)
    #pragma unroll
    for (int n = 0; n < 4; n++)
      acc2[m][n] = (f32x4){0.f, 0.f, 0.f, 0.f};
  #pragma unroll
  for (int ks = 0; ks < 2; ks++) {
    short8 a2[2];
    #pragma unroll
    for (int m = 0; m < 2; m++) {
      int row = m * 16 + r;
      int off = row * 128 + ks * 64 + g * 16;
      a2[m] = *(const short8*)(wnw + (off ^ ((r & 7) << 4)));
    }
    #pragma unroll
    for (int m = 0; m < 2; m++) {
      acc2[m][0] = MFMA(a2[m], bn2[ks][0], acc2[m][0]);
      acc2[m][1] = MFMA(a2[m], bn2[ks][1], acc2[m][1]);
      acc2[m][2] = MFMA(a2[m], bn2[ks][2], acc2[m][2]);
      acc2[m][3] = MFMA(a2[m], bn2[ks][3], acc2[m][3]);
    }
  }

  // ---- epilogue2: bias+relu, An-weighted reduce over this wave's 32 rows ----
  float x2p[4] = {0.f, 0.f, 0.f, 0.f};
  #pragma unroll
  for (int m = 0; m < 2; m++) {
    #pragma unroll
    for (int n = 0; n < 4; n++)
      #pragma unroll
      for (int reg = 0; reg < 4; reg++) {
        float e2 = fmaxf(acc2[m][n][reg] + bias2[n], 0.f);
        x2p[n] += (An8[m][reg] * inv) * e2;
      }
  }
  #pragma unroll
  for (int n = 0; n < 4; n++) {
    x2p[n] += __shfl_xor(x2p[n], 16, 64);
    x2p[n] += __shfl_xor(x2p[n], 32, 64);
  }
  if (l < 16) {
    float* dst = x2ws + bi * 512 + slot * 64;
    #pragma unroll
    for (int n = 0; n < 4; n++) dst[n * 16 + l] = x2p[n];   // normal store: node kernel reads it
  }
  // wave retires — no barrier, no tail.
}

// ---------------- node kernel: x_new = relu(concat(x, sum8(x2p)) @ w_n2n + b) -
__global__ __launch_bounds__(256) void gnn_node(
    const float* __restrict__ x, const float* __restrict__ w_n2n,
    const float* __restrict__ b_n2n, const float* __restrict__ x2ws,
    float* __restrict__ out)
{
  __shared__ float wl[128 * 64];      // 32KB, L2->LDS once per block
  __shared__ float xs[16][64];
  __shared__ float x2r[16][64];
  const int tid = threadIdx.x;
  const size_t bi0 = (size_t)blockIdx.x * 16;   // 128 blocks x 16 nodes

  #pragma unroll
  for (int i = 0; i < 8; i++)
    *(float4*)(&wl[(tid + i * 256) * 4]) = *(const float4*)(w_n2n + (tid + i * 256) * 4);
  *(float4*)(&xs[0][0] + tid * 4) = *(const float4*)(x + bi0 * 64 + tid * 4);
  {
    int rr = tid >> 4, fq = (tid & 15) * 4;
    const float* p = x2ws + (bi0 + rr) * 512 + fq;
    float4 sacc = {0.f, 0.f, 0.f, 0.f};
    #pragma unroll
    for (int q = 0; q < 8; q++) {
      float4 v = *(const float4*)(p + q * 64);
      sacc.x += v.x; sacc.y += v.y; sacc.z += v.z; sacc.w += v.w;
    }
    *(float4*)(&x2r[rr][fq]) = sacc;
  }
  __syncthreads();

  const int f = tid & 63, r0 = tid >> 6;
  #pragma unroll
  for (int it = 0; it < 4; it++) {
    int row = r0 * 4 + it;
    float s2 = b_n2n[f];
    #pragma unroll 8
    for (int k = 0; k < 64; k++) s2 += xs[row][k] * wl[k * 64 + f];
    #pragma unroll 8
    for (int k = 0; k < 64; k++) s2 += x2r[row][k] * wl[(64 + k) * 64 + f];
    __builtin_nontemporal_store(fmaxf(s2, 0.f),
        out + (size_t)8 * 256 * 256 * 64 + (bi0 + row) * 64 + f);
  }
}

// ---------------- fallback fused main (exact R6 best, used if ws too small) ---
__global__ __launch_bounds__(256, 2) void gnn_main_fused(
    const float* __restrict__ A, const float* __restrict__ W,
    const float* __restrict__ x,
    const float* __restrict__ b_e2e, const float* __restrict__ b_e2n,
    const float* __restrict__ w_n2n, const float* __restrict__ b_n2n,
    const unsigned short* __restrict__ x1ws,
    const unsigned short* __restrict__ wEf,
    const unsigned short* __restrict__ wNf,
    float* __restrict__ out)
{
  __shared__ __align__(16) float Arow[4][256];
  __shared__ float x2s[4][64];
  __shared__ __align__(16) char wn[4 * 8192];

  const int tid = threadIdx.x;
  const int w = tid >> 6, l = tid & 63, g = l >> 4, r = l & 15;
  const size_t bi = blockIdx.x;
  const int b = blockIdx.x >> 8;
  const int j0 = w * 64;

  const float* Wp = W + bi * 256 * 64;
  float4 wst[4][4];
  #pragma unroll
  for (int m = 0; m < 4; m++) {
    int jm = j0 + m * 16 + r;
    const float* p = Wp + (size_t)jm * 64 + g * 8;
    wst[m][0] = *(const float4*)(p);
    wst[m][1] = *(const float4*)(p + 4);
    wst[m][2] = *(const float4*)(p + 32);
    wst[m][3] = *(const float4*)(p + 36);
  }
  short8 x1st[4][2];
  #pragma unroll
  for (int m = 0; m < 4; m++) {
    int jm = j0 + m * 16 + r;
    const unsigned short* q = x1ws + ((size_t)(b * 256 + jm)) * 64 + g * 8;
    x1st[m][0] = *(const short8*)(q);
    x1st[m][1] = *(const short8*)(q + 32);
  }
  float4 av = *(const float4*)(A + bi * 256 + l * 4);
  *(float4*)(&Arow[w][l * 4]) = av;
  float s = fabsf(av.x) + fabsf(av.y) + fabsf(av.z) + fabsf(av.w);
  #pragma unroll
  for (int o = 32; o; o >>= 1) s += __shfl_xor(s, o, 64);
  const float inv = 1.0f / fmaxf(s, 1e-12f);
  short8 be[4][4];
  #pragma unroll
  for (int ks = 0; ks < 4; ks++)
    #pragma unroll
    for (int n = 0; n < 4; n++)
      be[ks][n] = *(const short8*)(wEf + (ks * 4 + n) * 512 + l * 8);
  __builtin_amdgcn_wave_barrier();
  short8 af[4][4];
  #pragma unroll
  for (int m = 0; m < 4; m++) {
    int jm = j0 + m * 16 + r;
    #pragma unroll
    for (int h = 0; h < 2; h++)
      af[m][h] = cvt8(wst[m][h * 2], wst[m][h * 2 + 1]);
    unsigned int msk = (Arow[w][jm] != 0.0f) ? 0xFFFFFFFFu : 0u;
    #pragma unroll
    for (int h = 0; h < 2; h++)
      af[m][2 + h] = mask8(x1st[m][h], msk);
  }
  f32x4 acc[4][4];
  #pragma unroll
  for (int m = 0; m < 4; m++)
    #pragma unroll
    for (int n = 0; n < 4; n++)
      acc[m][n] = (f32x4){0.f, 0.f, 0.f, 0.f};
  #pragma unroll
  for (int ks = 0; ks < 4; ks++)
    #pragma unroll
    for (int m = 0; m < 4; m++)
      #pragma unroll
      for (int n = 0; n < 4; n++)
        acc[m][n] = MFMA(af[m][ks], be[ks][n], acc[m][n]);
  float bias1[4];
  #pragma unroll
  for (int n = 0; n < 4; n++) bias1[n] = b_e2e[n * 16 + r];
  float* Wout = out + bi * 256 * 64;
  char* wnw = wn + w * 8192;
  #pragma unroll
  for (int m = 0; m < 4; m++)
    #pragma unroll
    for (int n = 0; n < 4; n++)
      #pragma unroll
      for (int reg = 0; reg < 4; reg++) {
        float v = fmaxf(acc[m][n][reg] + bias1[n], 0.f);
        int row = m * 16 + g * 4 + reg;
        int col = n * 16 + r;
        __builtin_nontemporal_store(v, Wout + (size_t)(j0 + row) * 64 + col);
        int off = row * 128 + col * 2;
        *(unsigned short*)(wnw + (off ^ ((row & 7) << 4))) = (unsigned short)f2bs(v);
      }
  short8 bn2[2][4];
  #pragma unroll
  for (int ks = 0; ks < 2; ks++)
    #pragma unroll
    for (int n = 0; n < 4; n++)
      bn2[ks][n] = *(const short8*)(wNf + (ks * 4 + n) * 512 + l * 8);
  f32x4 acc2[4][4];
  #pragma unroll
  for (int m = 0; m < 4; m++)
    #pragma unroll
    for (int n = 0; n < 4; n++)
      acc2[m][n] = (f32x4){0.f, 0.f, 0.f, 0.f};
  #pragma unroll
  for (int ks = 0; ks < 2; ks++) {
    short8 a2[4];
    #pragma unroll
    for (int m = 0; m < 4; m++) {
      int row = m * 16 + r;
      int off = row * 128 + ks * 64 + g * 16;
      a2[m] = *(const short8*)(wnw + (off ^ ((r & 7) << 4)));
    }
    #pragma unroll
    for (int m = 0; m < 4; m++)
      #pragma unroll
      for (int n = 0; n < 4; n++)
        acc2[m][n] = MFMA(a2[m], bn2[ks][n], acc2[m][n]);
  }
  float bias2[4];
  #pragma unroll
  for (int n = 0; n < 4; n++) bias2[n] = b_e2n[n * 16 + r];
  float x2p[4] = {0.f, 0.f, 0.f, 0.f};
  #pragma unroll
  for (int m = 0; m < 4; m++) {
    float An_[4];
    #pragma unroll
    for (int reg = 0; reg < 4; reg++)
      An_[reg] = Arow[w][j0 + m * 16 + g * 4 + reg] * inv;
    #pragma unroll
    for (int n = 0; n < 4; n++)
      #pragma unroll
      for (int reg = 0; reg < 4; reg++) {
        float e = fmaxf(acc2[m][n][reg] + bias2[n], 0.f);
        x2p[n] += An_[reg] * e;
      }
  }
  #pragma unroll
  for (int n = 0; n < 4; n++) {
    x2p[n] += __shfl_xor(x2p[n], 16, 64);
    x2p[n] += __shfl_xor(x2p[n], 32, 64);
  }
  if (l < 16) {
    #pragma unroll
    for (int n = 0; n < 4; n++) x2s[w][n * 16 + l] = x2p[n];
  }
  __syncthreads();
  if (tid < 64) {
    float s2 = b_n2n[tid];
    const float* xr = x + bi * 64;
    #pragma unroll 8
    for (int k = 0; k < 64; k++) s2 += xr[k] * w_n2n[k * 64 + tid];
    #pragma unroll 8
    for (int k = 0; k < 64; k++) {
      float x2k = x2s[0][k] + x2s[1][k] + x2s[2][k] + x2s[3][k];
      s2 += x2k * w_n2n[(64 + k) * 64 + tid];
    }
    __builtin_nontemporal_store(fmaxf(s2, 0.f),
                                out + (size_t)8 * 256 * 256 * 64 + bi * 64 + tid);
  }
}

extern "C" void kernel_launch(void* const* d_in, const int* in_sizes, int n_in,
                              void* d_out, int out_size, void* d_ws, size_t ws_size,
                              hipStream_t stream) {
  const float* A     = (const float*)d_in[0];
  const float* W     = (const float*)d_in[1];
  const float* x     = (const float*)d_in[2];
  const float* w_n2e = (const float*)d_in[3];
  const float* b_n2e = (const float*)d_in[4];
  const float* w_e2e = (const float*)d_in[5];
  const float* b_e2e = (const float*)d_in[6];
  const float* w_e2n = (const float*)d_in[7];
  const float* b_e2n = (const float*)d_in[8];
  const float* w_n2n = (const float*)d_in[9];
  const float* b_n2n = (const float*)d_in[10];

  unsigned short* x1ws = (unsigned short*)((char*)d_ws + WS_X1_OFF);
  unsigned short* wEf  = (unsigned short*)((char*)d_ws + WS_WE_OFF);
  unsigned short* wNf  = (unsigned short*)((char*)d_ws + WS_WN_OFF);
  float*          x2ws = (float*)((char*)d_ws + WS_X2_OFF);

  gnn_pre<<<518, 256, 0, stream>>>(x, w_n2e, b_n2e, w_e2e, w_e2n, x1ws, wEf, wNf);
  if (ws_size >= (size_t)WS_NEEDED) {
    gnn_main_nb<<<4096, 256, 0, stream>>>(A, W, b_e2e, b_e2n,
                                          x1ws, wEf, wNf, (float*)d_out, x2ws);
    gnn_node<<<128, 256, 0, stream>>>(x, w_n2n, b_n2n, x2ws, (float*)d_out);
  } else {
    gnn_main_fused<<<2048, 256, 0, stream>>>(A, W, x, b_e2e, b_e2n, w_n2n, b_n2n,
                                             x1ws, wEf, wNf, (float*)d_out);
  }
}